// Round 5
// baseline (109.470 us; speedup 1.0000x reference)
//
#include <hip/hip_runtime.h>

#define MK 4096
#define BK 128

typedef int v4i __attribute__((ext_vector_type(4)));
typedef int v16i __attribute__((ext_vector_type(16)));

#define MFMA32(a, b, c) __builtin_amdgcn_mfma_i32_32x32x32_i8(a, b, c, 0, 0, 0)

#define GLOAD_LDS16(gp, lp) \
  __builtin_amdgcn_global_load_lds((const __attribute__((address_space(1))) void*)(gp), \
                                   (__attribute__((address_space(3))) void*)(lp), 16, 0, 0)

#define SB() __builtin_amdgcn_sched_barrier(0)
#define BARRIER() __builtin_amdgcn_s_barrier()
#define WAIT_VM0() asm volatile("s_waitcnt vmcnt(0)" ::: "memory")
#define NOWAIT() ((void)0)

// ------- merged convert: blocks [0,2048) do mat1 int32->int8 (same layout);
//         blocks [2048,6144) do mat2 [K][N] int32 -> [N][K] int8 transpose --
__global__ __launch_bounds__(256) void cvt_kernel(const int* __restrict__ mat1,
                                                  char* __restrict__ A8,
                                                  const int* __restrict__ mat2,
                                                  char* __restrict__ B8T) {
  __shared__ char tile[64][68];
  if (blockIdx.x < 2048) {
    const int n4 = MK * MK / 4;
    int idx = blockIdx.x * 256 + threadIdx.x;
    const int stride = 2048 * 256;
    for (int i = idx; i < n4; i += stride) {
      int4 v = ((const int4*)mat1)[i];
      char4 c;
      c.x = (char)v.x; c.y = (char)v.y; c.z = (char)v.z; c.w = (char)v.w;
      ((char4*)A8)[i] = c;
    }
  } else {
    const int bid = blockIdx.x - 2048;
    const int t = threadIdx.x;
    const int n0 = (bid & 63) * 64, k0 = (bid >> 6) * 64;
#pragma unroll
    for (int r = 0; r < 16; ++r) {
      int k = k0 + r * 4 + (t >> 6);
      int n = n0 + (t & 63);
      tile[t & 63][r * 4 + (t >> 6)] = (char)mat2[(size_t)k * MK + n];
    }
    __syncthreads();
#pragma unroll
    for (int w = 0; w < 4; ++w) {
      int nl = w * 16 + (t >> 4);
      int kl = (t & 15) * 4;
      char4 c = *(const char4*)&tile[nl][kl];
      *(char4*)(B8T + (size_t)(n0 + nl) * MK + k0 + kl) = c;
    }
  }
}

// ---------------- i8 MFMA GEMM, 256x256 tile, 32x32x32 MFMA ----------------
// R10: barrier-per-TILE retained from R9, but stage pairs moved to phases
// 0-1 (two pairs per phase, still embedded AFTER each phase's 6 ds_reads --
// R7 showed clustering them BEFORE the ds_read storm collides write-back
// with the read critical path). R9's regression was drain cover, not the
// window depth: its last stage pair issued ~200cyc before the tile-end
// vmcnt(0) (marginal vs L2 latency), stalling every wave each tile. Now the
// last stage op has ~2.5 phases (~1500 CU-cyc) of MFMA cover, so vmcnt(0)
// drains instantly, phases 2-3 are pure compute, and the 33-barrier deep
// window can actually desync waves (one wave's ds_reads under another's
// MFMAs). Kept: 4x8 XCD rectangle swizzle (FETCH 106->82MB), merged cvt.
// LDS half layout (16 KiB): [blk:8][kk:2][r15:16][slot:4][16B],
// slot = (2*khalf + (row>>4)) ^ ((row&15)>>1 & 3)  (R4-verified 0-conflict).
__global__ __launch_bounds__(512, 2) void gemm_i8_kernel(const char* __restrict__ A8,
                                                         const char* __restrict__ B8T,
                                                         const int* __restrict__ inp,
                                                         float* __restrict__ out) {
  extern __shared__ char lds[];
  const int tid = threadIdx.x;
  const int wg = blockIdx.x;
  // XCD-aware 4x8 rectangle swizzle, bijective: xcd = wg&7 owns row-groups
  // [(xcd>>1)*4, +4) x col-groups [(xcd&1)*8, +8).
  const int xcd = wg & 7, loc = wg >> 3;
  const int m0 = (((xcd >> 1) << 2) + (loc >> 3)) << 8;
  const int n0 = (((xcd & 1) << 3) + (loc & 7)) << 8;

  const int lane = tid & 63, wid = tid >> 6;
  const int wr = wid >> 2, wc = wid & 3;
  const int rl = lane & 31;
  const int khalf = lane >> 5;

  // per-lane LDS read base: R2/R4's measured-0-conflict pattern
  const int r15 = lane & 15;
  const int slotr = (lane >> 4) ^ ((r15 >> 1) & 3);
  const char* pAr = lds + wr * 8192 + r15 * 64 + slotr * 16;
  const char* pBr = lds + 65536 + wc * 4096 + r15 * 64 + slotr * 16;

  // staging decode: thread t feeds LDS chunk idx=t (and idx+512 = +4 blks)
  const int sblk = tid >> 7;
  const int skk = (tid >> 6) & 1;
  const int sr15 = (tid >> 2) & 15;
  const int sslot = tid & 3;
  const int sx = sslot ^ ((sr15 >> 1) & 3);
  const int srow = sblk * 32 + (sx & 1) * 16 + sr15;
  const int skb = skk * 32 + (sx >> 1) * 16;
  const char* pA = A8 + (size_t)(m0 + srow) * MK + skb;
  const char* pB = B8T + (size_t)(n0 + srow) * MK + skb;
  char* ldsw = lds + (tid & ~63) * 16;  // wave-uniform dest base (+hw lane*16)

#define STAGE_A_(NB_, H_, TN_) do {                                               \
    const char* s_ = pA + (TN_)*BK + (H_)*64;                                     \
    GLOAD_LDS16(s_,                    ldsw + ((NB_)*32768 + (H_)*16384));        \
    GLOAD_LDS16(s_ + (size_t)128 * MK, ldsw + ((NB_)*32768 + (H_)*16384 + 8192)); \
  } while (0)
#define STAGE_B_(NB_, H_, TN_) do {                                               \
    const char* s_ = pB + (TN_)*BK + (H_)*64;                                     \
    GLOAD_LDS16(s_,                    ldsw + (65536 + (NB_)*32768 + (H_)*16384)); \
    GLOAD_LDS16(s_ + (size_t)128 * MK, ldsw + (65536 + (NB_)*32768 + (H_)*16384 + 8192)); \
  } while (0)
#define STAGE_AB_(NB_, H_, TN_) do { STAGE_A_(NB_, H_, TN_); STAGE_B_(NB_, H_, TN_); } while (0)

#define AOFF(B_, KK_, MB_) ((B_)*32768 + ((KK_) >> 1) * 16384 + (MB_)*2048 + ((KK_)&1) * 1024)
#define BOFF(B_, KK_, NB_) ((B_)*32768 + ((KK_) >> 1) * 16384 + (NB_)*2048 + ((KK_)&1) * 1024)

// one phase = one kk-step: 6 ds_read_b128 + optional stage ops + 8 MFMA.
// No barriers here: compiler inserts lgkmcnt; waves free-run within the tile.
#define PH(B_, KK_, STO_) do {                                                    \
    af0 = *(const v4i*)(pAr + AOFF(B_, KK_, 0));                                  \
    af1 = *(const v4i*)(pAr + AOFF(B_, KK_, 1));                                  \
    af2 = *(const v4i*)(pAr + AOFF(B_, KK_, 2));                                  \
    af3 = *(const v4i*)(pAr + AOFF(B_, KK_, 3));                                  \
    bf0 = *(const v4i*)(pBr + BOFF(B_, KK_, 0));                                  \
    bf1 = *(const v4i*)(pBr + BOFF(B_, KK_, 1));                                  \
    STO_;                                                                         \
    __builtin_amdgcn_s_setprio(1);                                                \
    acc[0][0] = MFMA32(af0, bf0, acc[0][0]); acc[0][1] = MFMA32(af0, bf1, acc[0][1]); \
    acc[1][0] = MFMA32(af1, bf0, acc[1][0]); acc[1][1] = MFMA32(af1, bf1, acc[1][1]); \
    acc[2][0] = MFMA32(af2, bf0, acc[2][0]); acc[2][1] = MFMA32(af2, bf1, acc[2][1]); \
    acc[3][0] = MFMA32(af3, bf0, acc[3][0]); acc[3][1] = MFMA32(af3, bf1, acc[3][1]); \
    __builtin_amdgcn_s_setprio(0);                                                \
  } while (0)

// full K-tile region: stages embedded in phases 0-1 (mid-phase), phases 2-3
// pure compute, then ONE vmcnt(0)+barrier. The drain is free: last stage op
// issued ~2.5 phases before it.
#define TILE(B_, TN_, DOST_) do {                                                 \
    if (DOST_) { PH(B_, 0, STAGE_AB_((B_) ^ 1, 0, TN_));                          \
                 PH(B_, 1, STAGE_AB_((B_) ^ 1, 1, TN_));                          \
                 PH(B_, 2, NOWAIT()); PH(B_, 3, NOWAIT()); }                      \
    else       { PH(B_, 0, NOWAIT()); PH(B_, 1, NOWAIT());                        \
                 PH(B_, 2, NOWAIT()); PH(B_, 3, NOWAIT()); }                      \
    SB(); WAIT_VM0(); BARRIER(); SB();                                            \
  } while (0)

  v16i acc[4][2];
#pragma unroll
  for (int m = 0; m < 4; ++m)
#pragma unroll
    for (int n = 0; n < 2; ++n)
#pragma unroll
      for (int i = 0; i < 16; ++i) acc[m][n][i] = 0;
  v4i af0, af1, af2, af3, bf0, bf1;

  // prologue: stage tile 0 -> buf0 (8 loads), drain all, sync
  STAGE_A_(0, 0, 0); STAGE_B_(0, 0, 0); STAGE_A_(0, 1, 0); STAGE_B_(0, 1, 0);
  WAIT_VM0(); BARRIER(); SB();

#pragma unroll 1
  for (int it = 0; it < 15; ++it) {
    TILE(0, 2 * it + 1, 1);   // tile 2it   in buf0, stages 2it+1 -> buf1
    TILE(1, 2 * it + 2, 1);   // tile 2it+1 in buf1, stages 2it+2 -> buf0
  }
  TILE(0, 31, 1);             // tile 30 in buf0, stages 31 -> buf1
  // tile 31 in buf1: no staging, no trailing sync
  PH(1, 0, NOWAIT()); PH(1, 1, NOWAIT()); PH(1, 2, NOWAIT()); PH(1, 3, NOWAIT());

  // epilogue: 32x32 C/D layout col=lane&31, row=(reg&3)+8*(reg>>2)+4*khalf
#pragma unroll
  for (int mb = 0; mb < 4; ++mb) {
#pragma unroll
    for (int nb = 0; nb < 2; ++nb) {
      const int col = n0 + wc * 64 + nb * 32 + rl;
      const int row0 = m0 + wr * 128 + mb * 32 + 4 * khalf;
#pragma unroll
      for (int r = 0; r < 16; ++r) {
        const int row = row0 + (r & 3) + 8 * (r >> 2);
        const size_t idx = (size_t)row * MK + col;
        const int v = acc[mb][nb][r] + __builtin_nontemporal_load(inp + idx);
        __builtin_nontemporal_store((float)v, out + idx);
      }
    }
  }
}

// ---------------- fallback (only if ws too small): naive tiled int32 -------
__global__ void fallback_kernel(const int* __restrict__ mat1, const int* __restrict__ mat2,
                                const int* __restrict__ inp, float* __restrict__ out) {
  __shared__ int As[16][16], Bs[16][17];
  int tx = threadIdx.x, ty = threadIdx.y;
  int row = blockIdx.y * 16 + ty, col = blockIdx.x * 16 + tx;
  int acc = 0;
  for (int kt = 0; kt < MK / 16; ++kt) {
    As[ty][tx] = mat1[(size_t)row * MK + kt * 16 + tx];
    Bs[ty][tx] = mat2[(size_t)(kt * 16 + ty) * MK + col];
    __syncthreads();
#pragma unroll
    for (int k = 0; k < 16; ++k) acc += As[ty][k] * Bs[k][tx];
    __syncthreads();
  }
  size_t idx = (size_t)row * MK + col;
  out[idx] = (float)(acc + inp[idx]);
}

extern "C" void kernel_launch(void* const* d_in, const int* in_sizes, int n_in,
                              void* d_out, int out_size, void* d_ws, size_t ws_size,
                              hipStream_t stream) {
  const int* inp = (const int*)d_in[0];
  const int* mat1 = (const int*)d_in[1];
  const int* mat2 = (const int*)d_in[2];
  float* out = (float*)d_out;

  const size_t need = 2 * (size_t)MK * MK;
  if (ws_size >= need) {
    char* A8 = (char*)d_ws;
    char* B8T = A8 + (size_t)MK * MK;
    cvt_kernel<<<6144, 256, 0, stream>>>(mat1, A8, mat2, B8T);
    (void)hipFuncSetAttribute((const void*)gemm_i8_kernel,
                              hipFuncAttributeMaxDynamicSharedMemorySize, 131072);
    gemm_i8_kernel<<<256, 512, 131072, stream>>>(A8, B8T, inp, out);
  } else {
    dim3 blk(16, 16), grd(MK / 16, MK / 16);
    fallback_kernel<<<grd, blk, 0, stream>>>(mat1, mat2, inp, out);
  }
}

// Round 6
// 101.773 us; speedup vs baseline: 1.0756x; 1.0756x over previous
//
#include <hip/hip_runtime.h>

#define MK 4096
#define BK 128

typedef int v4i __attribute__((ext_vector_type(4)));
typedef int v16i __attribute__((ext_vector_type(16)));

#define MFMA32(a, b, c) __builtin_amdgcn_mfma_i32_32x32x32_i8(a, b, c, 0, 0, 0)

#define GLOAD_LDS16(gp, lp) \
  __builtin_amdgcn_global_load_lds((const __attribute__((address_space(1))) void*)(gp), \
                                   (__attribute__((address_space(3))) void*)(lp), 16, 0, 0)

#define SB() __builtin_amdgcn_sched_barrier(0)
#define BARRIER() __builtin_amdgcn_s_barrier()
#define WAIT_VM4() asm volatile("s_waitcnt vmcnt(4)" ::: "memory")
#define WAIT_VM0() asm volatile("s_waitcnt vmcnt(0)" ::: "memory")
#define NOWAIT() ((void)0)

// ------- merged convert: blocks [0,2048) do mat1 int32->int8 (same layout);
//         blocks [2048,6144) do mat2 [K][N] int32 -> [N][K] int8 transpose --
__global__ __launch_bounds__(256) void cvt_kernel(const int* __restrict__ mat1,
                                                  char* __restrict__ A8,
                                                  const int* __restrict__ mat2,
                                                  char* __restrict__ B8T) {
  __shared__ char tile[64][68];
  if (blockIdx.x < 2048) {
    const int n4 = MK * MK / 4;
    int idx = blockIdx.x * 256 + threadIdx.x;
    const int stride = 2048 * 256;
    for (int i = idx; i < n4; i += stride) {
      int4 v = ((const int4*)mat1)[i];
      char4 c;
      c.x = (char)v.x; c.y = (char)v.y; c.z = (char)v.z; c.w = (char)v.w;
      ((char4*)A8)[i] = c;
    }
  } else {
    const int bid = blockIdx.x - 2048;
    const int t = threadIdx.x;
    const int n0 = (bid & 63) * 64, k0 = (bid >> 6) * 64;
#pragma unroll
    for (int r = 0; r < 16; ++r) {
      int k = k0 + r * 4 + (t >> 6);
      int n = n0 + (t & 63);
      tile[t & 63][r * 4 + (t >> 6)] = (char)mat2[(size_t)k * MK + n];
    }
    __syncthreads();
#pragma unroll
    for (int w = 0; w < 4; ++w) {
      int nl = w * 16 + (t >> 4);
      int kl = (t & 15) * 4;
      char4 c = *(const char4*)&tile[nl][kl];
      *(char4*)(B8T + (size_t)(n0 + nl) * MK + k0 + kl) = c;
    }
  }
}

// ---------------- i8 MFMA GEMM, 256x256 tile, 32x32x32 MFMA ----------------
// R11: R8 EXACT revert (best: gemm 79.0us). R9/R10 established that the
// two-barrier-per-tile scheme is a publish-in-two-installments design whose
// invariants all alternatives broke: (a) counted vmcnt(4) always waits on
// loads issued a full half (~1200cyc) earlier -> zero drain stalls; (b)
// stage issue + LDS write-back stay spread (LDS pipe is ~87% loaded:
// 384cyc reads + 128cyc writes vs 585cyc MFMA per phase per CU); (c) no
// barrier-adjacent wait transitively covers a young load. Single tweak on
// R8: PH reads bf0 FIRST and MFMAs issue B-major, so the first MFMA's
// operands are the first two reads (lgkmcnt releases at 4 outstanding, not
// 1) -- shaves post-barrier latency at the 64 half-starts. Kept: 4x8 XCD
// rectangle swizzle (FETCH 106->82MB), merged cvt, mid-phase stage embed.
// LDS half layout (16 KiB): [blk:8][kk:2][r15:16][slot:4][16B],
// slot = (2*khalf + (row>>4)) ^ ((row&15)>>1 & 3)  (R4-verified 0-conflict).
__global__ __launch_bounds__(512, 2) void gemm_i8_kernel(const char* __restrict__ A8,
                                                         const char* __restrict__ B8T,
                                                         const int* __restrict__ inp,
                                                         float* __restrict__ out) {
  extern __shared__ char lds[];
  const int tid = threadIdx.x;
  const int wg = blockIdx.x;
  // XCD-aware 4x8 rectangle swizzle, bijective: xcd = wg&7 owns row-groups
  // [(xcd>>1)*4, +4) x col-groups [(xcd&1)*8, +8).
  const int xcd = wg & 7, loc = wg >> 3;
  const int m0 = (((xcd >> 1) << 2) + (loc >> 3)) << 8;
  const int n0 = (((xcd & 1) << 3) + (loc & 7)) << 8;

  const int lane = tid & 63, wid = tid >> 6;
  const int wr = wid >> 2, wc = wid & 3;
  const int rl = lane & 31;
  const int khalf = lane >> 5;

  // per-lane LDS read base: R2/R4's measured-0-conflict pattern
  const int r15 = lane & 15;
  const int slotr = (lane >> 4) ^ ((r15 >> 1) & 3);
  const char* pAr = lds + wr * 8192 + r15 * 64 + slotr * 16;
  const char* pBr = lds + 65536 + wc * 4096 + r15 * 64 + slotr * 16;

  // staging decode: thread t feeds LDS chunk idx=t (and idx+512 = +4 blks)
  const int sblk = tid >> 7;
  const int skk = (tid >> 6) & 1;
  const int sr15 = (tid >> 2) & 15;
  const int sslot = tid & 3;
  const int sx = sslot ^ ((sr15 >> 1) & 3);
  const int srow = sblk * 32 + (sx & 1) * 16 + sr15;
  const int skb = skk * 32 + (sx >> 1) * 16;
  const char* pA = A8 + (size_t)(m0 + srow) * MK + skb;
  const char* pB = B8T + (size_t)(n0 + srow) * MK + skb;
  char* ldsw = lds + (tid & ~63) * 16;  // wave-uniform dest base (+hw lane*16)

#define STAGE_A_(NB_, H_, TN_) do {                                               \
    const char* s_ = pA + (TN_)*BK + (H_)*64;                                     \
    GLOAD_LDS16(s_,                    ldsw + ((NB_)*32768 + (H_)*16384));        \
    GLOAD_LDS16(s_ + (size_t)128 * MK, ldsw + ((NB_)*32768 + (H_)*16384 + 8192)); \
  } while (0)
#define STAGE_B_(NB_, H_, TN_) do {                                               \
    const char* s_ = pB + (TN_)*BK + (H_)*64;                                     \
    GLOAD_LDS16(s_,                    ldsw + (65536 + (NB_)*32768 + (H_)*16384)); \
    GLOAD_LDS16(s_ + (size_t)128 * MK, ldsw + (65536 + (NB_)*32768 + (H_)*16384 + 8192)); \
  } while (0)

#define AOFF(B_, KK_, MB_) ((B_)*32768 + ((KK_) >> 1) * 16384 + (MB_)*2048 + ((KK_)&1) * 1024)
#define BOFF(B_, KK_, NB_) ((B_)*32768 + ((KK_) >> 1) * 16384 + (NB_)*2048 + ((KK_)&1) * 1024)

// one phase = one kk-step: 6 ds_read_b128 + optional stage-pair + 8 MFMA.
// Reads ordered bf0-first, MFMAs B-major: first MFMA needs only the first
// two reads -> lgkmcnt releases at 4 outstanding (was 1), cutting the
// post-barrier latency exposure. No barriers here: compiler inserts
// lgkmcnt; waves free-run within the half.
#define PH(B_, KK_, STO_) do {                                                    \
    bf0 = *(const v4i*)(pBr + BOFF(B_, KK_, 0));                                  \
    af0 = *(const v4i*)(pAr + AOFF(B_, KK_, 0));                                  \
    af1 = *(const v4i*)(pAr + AOFF(B_, KK_, 1));                                  \
    af2 = *(const v4i*)(pAr + AOFF(B_, KK_, 2));                                  \
    af3 = *(const v4i*)(pAr + AOFF(B_, KK_, 3));                                  \
    bf1 = *(const v4i*)(pBr + BOFF(B_, KK_, 1));                                  \
    STO_;                                                                         \
    __builtin_amdgcn_s_setprio(1);                                                \
    acc[0][0] = MFMA32(af0, bf0, acc[0][0]); acc[1][0] = MFMA32(af1, bf0, acc[1][0]); \
    acc[2][0] = MFMA32(af2, bf0, acc[2][0]); acc[3][0] = MFMA32(af3, bf0, acc[3][0]); \
    acc[0][1] = MFMA32(af0, bf1, acc[0][1]); acc[1][1] = MFMA32(af1, bf1, acc[1][1]); \
    acc[2][1] = MFMA32(af2, bf1, acc[2][1]); acc[3][1] = MFMA32(af3, bf1, acc[3][1]); \
    __builtin_amdgcn_s_setprio(0);                                                \
  } while (0)

// half-tile region: 2 phases, then vmcnt+barrier (the ONLY sync per half).
// FIFO invariant: at each half-end, queue = 8 outstanding; vmcnt(4) drains
// exactly the half the next region reads.
#define HALF(B_, H_, TN_, DOST_, VMW_) do {                                       \
    if (DOST_) { PH(B_, 2*(H_), STAGE_A_((B_) ^ 1, H_, TN_));                     \
                 PH(B_, 2*(H_) + 1, STAGE_B_((B_) ^ 1, H_, TN_)); }               \
    else       { PH(B_, 2*(H_), NOWAIT()); PH(B_, 2*(H_) + 1, NOWAIT()); }        \
    SB(); VMW_; BARRIER(); SB();                                                  \
  } while (0)

  v16i acc[4][2];
#pragma unroll
  for (int m = 0; m < 4; ++m)
#pragma unroll
    for (int n = 0; n < 2; ++n)
#pragma unroll
      for (int i = 0; i < 16; ++i) acc[m][n][i] = 0;
  v4i af0, af1, af2, af3, bf0, bf1;

  // prologue: stage tile 0 -> buf0 (8 loads), drain h0, sync
  STAGE_A_(0, 0, 0); STAGE_B_(0, 0, 0); STAGE_A_(0, 1, 0); STAGE_B_(0, 1, 0);
  WAIT_VM4(); BARRIER(); SB();

#pragma unroll 1
  for (int it = 0; it < 15; ++it) {
    HALF(0, 0, 2 * it + 1, 1, WAIT_VM4());
    HALF(0, 1, 2 * it + 1, 1, WAIT_VM4());
    HALF(1, 0, 2 * it + 2, 1, WAIT_VM4());
    HALF(1, 1, 2 * it + 2, 1, WAIT_VM4());
  }
  HALF(0, 0, 31, 1, WAIT_VM4());
  HALF(0, 1, 31, 1, WAIT_VM4());
  // tile 31: no staging; h0 must drain h1's loads fully before h1 reads
  HALF(1, 0, 0, 0, WAIT_VM0());
  PH(1, 2, NOWAIT()); PH(1, 3, NOWAIT());  // last half, no sync needed after

  // epilogue: 32x32 C/D layout col=lane&31, row=(reg&3)+8*(reg>>2)+4*khalf
#pragma unroll
  for (int mb = 0; mb < 4; ++mb) {
#pragma unroll
    for (int nb = 0; nb < 2; ++nb) {
      const int col = n0 + wc * 64 + nb * 32 + rl;
      const int row0 = m0 + wr * 128 + mb * 32 + 4 * khalf;
#pragma unroll
      for (int r = 0; r < 16; ++r) {
        const int row = row0 + (r & 3) + 8 * (r >> 2);
        const size_t idx = (size_t)row * MK + col;
        const int v = acc[mb][nb][r] + __builtin_nontemporal_load(inp + idx);
        __builtin_nontemporal_store((float)v, out + idx);
      }
    }
  }
}

// ---------------- fallback (only if ws too small): naive tiled int32 -------
__global__ void fallback_kernel(const int* __restrict__ mat1, const int* __restrict__ mat2,
                                const int* __restrict__ inp, float* __restrict__ out) {
  __shared__ int As[16][16], Bs[16][17];
  int tx = threadIdx.x, ty = threadIdx.y;
  int row = blockIdx.y * 16 + ty, col = blockIdx.x * 16 + tx;
  int acc = 0;
  for (int kt = 0; kt < MK / 16; ++kt) {
    As[ty][tx] = mat1[(size_t)row * MK + kt * 16 + tx];
    Bs[ty][tx] = mat2[(size_t)(kt * 16 + ty) * MK + col];
    __syncthreads();
#pragma unroll
    for (int k = 0; k < 16; ++k) acc += As[ty][k] * Bs[k][tx];
    __syncthreads();
  }
  size_t idx = (size_t)row * MK + col;
  out[idx] = (float)(acc + inp[idx]);
}

extern "C" void kernel_launch(void* const* d_in, const int* in_sizes, int n_in,
                              void* d_out, int out_size, void* d_ws, size_t ws_size,
                              hipStream_t stream) {
  const int* inp = (const int*)d_in[0];
  const int* mat1 = (const int*)d_in[1];
  const int* mat2 = (const int*)d_in[2];
  float* out = (float*)d_out;

  const size_t need = 2 * (size_t)MK * MK;
  if (ws_size >= need) {
    char* A8 = (char*)d_ws;
    char* B8T = A8 + (size_t)MK * MK;
    cvt_kernel<<<6144, 256, 0, stream>>>(mat1, A8, mat2, B8T);
    (void)hipFuncSetAttribute((const void*)gemm_i8_kernel,
                              hipFuncAttributeMaxDynamicSharedMemorySize, 131072);
    gemm_i8_kernel<<<256, 512, 131072, stream>>>(A8, B8T, inp, out);
  } else {
    dim3 blk(16, 16), grd(MK / 16, MK / 16);
    fallback_kernel<<<grd, blk, 0, stream>>>(mat1, mat2, inp, out);
  }
}

// Round 7
// 101.339 us; speedup vs baseline: 1.0802x; 1.0043x over previous
//
#include <hip/hip_runtime.h>

#define MK 4096
#define BK 128

typedef int v4i __attribute__((ext_vector_type(4)));
typedef int v16i __attribute__((ext_vector_type(16)));

#define MFMA32(a, b, c) __builtin_amdgcn_mfma_i32_32x32x32_i8(a, b, c, 0, 0, 0)

#define GLOAD_LDS16(gp, lp) \
  __builtin_amdgcn_global_load_lds((const __attribute__((address_space(1))) void*)(gp), \
                                   (__attribute__((address_space(3))) void*)(lp), 16, 0, 0)

#define SB() __builtin_amdgcn_sched_barrier(0)
#define BARRIER() __builtin_amdgcn_s_barrier()
#define WAIT_VM4() asm volatile("s_waitcnt vmcnt(4)" ::: "memory")
#define WAIT_VM0() asm volatile("s_waitcnt vmcnt(0)" ::: "memory")
#define NOWAIT() ((void)0)

// ------- merged convert: blocks [0,2048) do mat1 int32->int8 (same layout);
//         blocks [2048,6144) do mat2 [K][N] int32 -> [N][K] int8 transpose --
__global__ __launch_bounds__(256) void cvt_kernel(const int* __restrict__ mat1,
                                                  char* __restrict__ A8,
                                                  const int* __restrict__ mat2,
                                                  char* __restrict__ B8T) {
  __shared__ char tile[64][68];
  if (blockIdx.x < 2048) {
    const int n4 = MK * MK / 4;
    int idx = blockIdx.x * 256 + threadIdx.x;
    const int stride = 2048 * 256;
    for (int i = idx; i < n4; i += stride) {
      int4 v = ((const int4*)mat1)[i];
      char4 c;
      c.x = (char)v.x; c.y = (char)v.y; c.z = (char)v.z; c.w = (char)v.w;
      ((char4*)A8)[i] = c;
    }
  } else {
    const int bid = blockIdx.x - 2048;
    const int t = threadIdx.x;
    const int n0 = (bid & 63) * 64, k0 = (bid >> 6) * 64;
#pragma unroll
    for (int r = 0; r < 16; ++r) {
      int k = k0 + r * 4 + (t >> 6);
      int n = n0 + (t & 63);
      tile[t & 63][r * 4 + (t >> 6)] = (char)mat2[(size_t)k * MK + n];
    }
    __syncthreads();
#pragma unroll
    for (int w = 0; w < 4; ++w) {
      int nl = w * 16 + (t >> 4);
      int kl = (t & 15) * 4;
      char4 c = *(const char4*)&tile[nl][kl];
      *(char4*)(B8T + (size_t)(n0 + nl) * MK + k0 + kl) = c;
    }
  }
}

// ---------------- i8 MFMA GEMM, 256x256 tile, 32x32x32 MFMA ----------------
// R12: R11/R8 structure + WAVE-SKEWED PHASE ORDER. The ~20us main-loop gap
// over the MFMA floor is post-barrier latency exposure: all 8 waves leave
// each of the 64 barriers in lockstep and SIMD-mates (wid, wid+4) issue
// their phase-0 ds_read storms simultaneously -- neither covers the other's
// LDS latency. Fix: the two kk-steps of a half are order-commutative (same
// published buffer, integer adds), so waves 0-3 consume (kk0,kk1) and waves
// 4-7 consume (kk1,kk0). Branch-free via dual LDS base pointers (the kk-
// dependent term is o*1024; 1024B is bank-aligned so bank patterns are
// unchanged). Per-wave VMEM issue order untouched (stage_A in the first-
// executed phase, stage_B in the second) -> R8 FIFO invariants hold:
// (a) vmcnt(4) waits only on loads >=1 half old, (b) stage issue+write-back
// spread mid-phase, (c) no wait covers a young load.
// Kept: 4x8 XCD rectangle swizzle (FETCH 106->82MB), merged cvt, bf0-first/
// B-major MFMA order (neutral), mid-phase stage embed.
// LDS half layout (16 KiB): [blk:8][kk:2][r15:16][slot:4][16B],
// slot = (2*khalf + (row>>4)) ^ ((row&15)>>1 & 3)  (R4-verified 0-conflict).
__global__ __launch_bounds__(512, 2) void gemm_i8_kernel(const char* __restrict__ A8,
                                                         const char* __restrict__ B8T,
                                                         const int* __restrict__ inp,
                                                         float* __restrict__ out) {
  extern __shared__ char lds[];
  const int tid = threadIdx.x;
  const int wg = blockIdx.x;
  // XCD-aware 4x8 rectangle swizzle, bijective: xcd = wg&7 owns row-groups
  // [(xcd>>1)*4, +4) x col-groups [(xcd&1)*8, +8).
  const int xcd = wg & 7, loc = wg >> 3;
  const int m0 = (((xcd >> 1) << 2) + (loc >> 3)) << 8;
  const int n0 = (((xcd & 1) << 3) + (loc & 7)) << 8;

  const int lane = tid & 63, wid = tid >> 6;
  const int wr = wid >> 2, wc = wid & 3;
  const int rl = lane & 31;
  const int khalf = lane >> 5;

  // per-lane LDS read base: R2/R4's measured-0-conflict pattern
  const int r15 = lane & 15;
  const int slotr = (lane >> 4) ^ ((r15 >> 1) & 3);
  const char* pAr = lds + wr * 8192 + r15 * 64 + slotr * 16;
  const char* pBr = lds + 65536 + wc * 4096 + r15 * 64 + slotr * 16;

  // wave-skewed kk order: SIMD-mates (wid, wid+4) take opposite orders.
  const int oF = (wid >> 2) & 1;           // first-consumed kk parity
  const char* pArF = pAr + oF * 1024;
  const char* pArS = pAr + (oF ^ 1) * 1024;
  const char* pBrF = pBr + oF * 1024;
  const char* pBrS = pBr + (oF ^ 1) * 1024;

  // staging decode: thread t feeds LDS chunk idx=t (and idx+512 = +4 blks)
  const int sblk = tid >> 7;
  const int skk = (tid >> 6) & 1;
  const int sr15 = (tid >> 2) & 15;
  const int sslot = tid & 3;
  const int sx = sslot ^ ((sr15 >> 1) & 3);
  const int srow = sblk * 32 + (sx & 1) * 16 + sr15;
  const int skb = skk * 32 + (sx >> 1) * 16;
  const char* pA = A8 + (size_t)(m0 + srow) * MK + skb;
  const char* pB = B8T + (size_t)(n0 + srow) * MK + skb;
  char* ldsw = lds + (tid & ~63) * 16;  // wave-uniform dest base (+hw lane*16)

#define STAGE_A_(NB_, H_, TN_) do {                                               \
    const char* s_ = pA + (TN_)*BK + (H_)*64;                                     \
    GLOAD_LDS16(s_,                    ldsw + ((NB_)*32768 + (H_)*16384));        \
    GLOAD_LDS16(s_ + (size_t)128 * MK, ldsw + ((NB_)*32768 + (H_)*16384 + 8192)); \
  } while (0)
#define STAGE_B_(NB_, H_, TN_) do {                                               \
    const char* s_ = pB + (TN_)*BK + (H_)*64;                                     \
    GLOAD_LDS16(s_,                    ldsw + (65536 + (NB_)*32768 + (H_)*16384)); \
    GLOAD_LDS16(s_ + (size_t)128 * MK, ldsw + (65536 + (NB_)*32768 + (H_)*16384 + 8192)); \
  } while (0)

// kk-independent LDS fragment offsets (the kk parity lives in the F/S base
// pointers): OFF = B*32768 + H*16384 + blk*2048.
#define AOFF2(B_, H_, MB_) ((B_)*32768 + (H_)*16384 + (MB_)*2048)
#define BOFF2(B_, H_, NB_) ((B_)*32768 + (H_)*16384 + (NB_)*2048)

// one phase = one kk-step from base-pointer set (PA_,PB_): 6 ds_read_b128 +
// optional stage-pair + 8 MFMA. bf0-first reads, B-major MFMAs: first MFMA
// needs only the first two reads -> lgkmcnt releases at 4 outstanding.
// No barriers here: compiler inserts lgkmcnt; waves free-run within the half.
#define PHO(B_, H_, PA_, PB_, STO_) do {                                          \
    bf0 = *(const v4i*)(PB_ + BOFF2(B_, H_, 0));                                  \
    af0 = *(const v4i*)(PA_ + AOFF2(B_, H_, 0));                                  \
    af1 = *(const v4i*)(PA_ + AOFF2(B_, H_, 1));                                  \
    af2 = *(const v4i*)(PA_ + AOFF2(B_, H_, 2));                                  \
    af3 = *(const v4i*)(PA_ + AOFF2(B_, H_, 3));                                  \
    bf1 = *(const v4i*)(PB_ + BOFF2(B_, H_, 1));                                  \
    STO_;                                                                         \
    __builtin_amdgcn_s_setprio(1);                                                \
    acc[0][0] = MFMA32(af0, bf0, acc[0][0]); acc[1][0] = MFMA32(af1, bf0, acc[1][0]); \
    acc[2][0] = MFMA32(af2, bf0, acc[2][0]); acc[3][0] = MFMA32(af3, bf0, acc[3][0]); \
    acc[0][1] = MFMA32(af0, bf1, acc[0][1]); acc[1][1] = MFMA32(af1, bf1, acc[1][1]); \
    acc[2][1] = MFMA32(af2, bf1, acc[2][1]); acc[3][1] = MFMA32(af3, bf1, acc[3][1]); \
    __builtin_amdgcn_s_setprio(0);                                                \
  } while (0)

// half-tile region: 2 phases (F-order then S-order; SIMD-mates have opposite
// parities so their read/MFMA windows interleave), then vmcnt+barrier (the
// ONLY sync per half). FIFO invariant: at each half-end, queue = 8
// outstanding; vmcnt(4) drains exactly the half the next region reads.
#define HALF(B_, H_, TN_, DOST_, VMW_) do {                                       \
    if (DOST_) { PHO(B_, H_, pArF, pBrF, STAGE_A_((B_) ^ 1, H_, TN_));            \
                 PHO(B_, H_, pArS, pBrS, STAGE_B_((B_) ^ 1, H_, TN_)); }          \
    else       { PHO(B_, H_, pArF, pBrF, NOWAIT());                               \
                 PHO(B_, H_, pArS, pBrS, NOWAIT()); }                             \
    SB(); VMW_; BARRIER(); SB();                                                  \
  } while (0)

  v16i acc[4][2];
#pragma unroll
  for (int m = 0; m < 4; ++m)
#pragma unroll
    for (int n = 0; n < 2; ++n)
#pragma unroll
      for (int i = 0; i < 16; ++i) acc[m][n][i] = 0;
  v4i af0, af1, af2, af3, bf0, bf1;

  // prologue: stage tile 0 -> buf0 (8 loads), drain h0, sync
  STAGE_A_(0, 0, 0); STAGE_B_(0, 0, 0); STAGE_A_(0, 1, 0); STAGE_B_(0, 1, 0);
  WAIT_VM4(); BARRIER(); SB();

#pragma unroll 1
  for (int it = 0; it < 15; ++it) {
    HALF(0, 0, 2 * it + 1, 1, WAIT_VM4());
    HALF(0, 1, 2 * it + 1, 1, WAIT_VM4());
    HALF(1, 0, 2 * it + 2, 1, WAIT_VM4());
    HALF(1, 1, 2 * it + 2, 1, WAIT_VM4());
  }
  HALF(0, 0, 31, 1, WAIT_VM4());
  HALF(0, 1, 31, 1, WAIT_VM4());
  // tile 31: no staging; h0 must drain h1's loads fully before h1 reads
  HALF(1, 0, 0, 0, WAIT_VM0());
  PHO(1, 1, pArF, pBrF, NOWAIT()); PHO(1, 1, pArS, pBrS, NOWAIT());  // last half

  // epilogue: 32x32 C/D layout col=lane&31, row=(reg&3)+8*(reg>>2)+4*khalf
#pragma unroll
  for (int mb = 0; mb < 4; ++mb) {
#pragma unroll
    for (int nb = 0; nb < 2; ++nb) {
      const int col = n0 + wc * 64 + nb * 32 + rl;
      const int row0 = m0 + wr * 128 + mb * 32 + 4 * khalf;
#pragma unroll
      for (int r = 0; r < 16; ++r) {
        const int row = row0 + (r & 3) + 8 * (r >> 2);
        const size_t idx = (size_t)row * MK + col;
        const int v = acc[mb][nb][r] + __builtin_nontemporal_load(inp + idx);
        __builtin_nontemporal_store((float)v, out + idx);
      }
    }
  }
}

// ---------------- fallback (only if ws too small): naive tiled int32 -------
__global__ void fallback_kernel(const int* __restrict__ mat1, const int* __restrict__ mat2,
                                const int* __restrict__ inp, float* __restrict__ out) {
  __shared__ int As[16][16], Bs[16][17];
  int tx = threadIdx.x, ty = threadIdx.y;
  int row = blockIdx.y * 16 + ty, col = blockIdx.x * 16 + tx;
  int acc = 0;
  for (int kt = 0; kt < MK / 16; ++kt) {
    As[ty][tx] = mat1[(size_t)row * MK + kt * 16 + tx];
    Bs[ty][tx] = mat2[(size_t)(kt * 16 + ty) * MK + col];
    __syncthreads();
#pragma unroll
    for (int k = 0; k < 16; ++k) acc += As[ty][k] * Bs[k][tx];
    __syncthreads();
  }
  size_t idx = (size_t)row * MK + col;
  out[idx] = (float)(acc + inp[idx]);
}

extern "C" void kernel_launch(void* const* d_in, const int* in_sizes, int n_in,
                              void* d_out, int out_size, void* d_ws, size_t ws_size,
                              hipStream_t stream) {
  const int* inp = (const int*)d_in[0];
  const int* mat1 = (const int*)d_in[1];
  const int* mat2 = (const int*)d_in[2];
  float* out = (float*)d_out;

  const size_t need = 2 * (size_t)MK * MK;
  if (ws_size >= need) {
    char* A8 = (char*)d_ws;
    char* B8T = A8 + (size_t)MK * MK;
    cvt_kernel<<<6144, 256, 0, stream>>>(mat1, A8, mat2, B8T);
    (void)hipFuncSetAttribute((const void*)gemm_i8_kernel,
                              hipFuncAttributeMaxDynamicSharedMemorySize, 131072);
    gemm_i8_kernel<<<256, 512, 131072, stream>>>(A8, B8T, inp, out);
  } else {
    dim3 blk(16, 16), grd(MK / 16, MK / 16);
    fallback_kernel<<<grd, blk, 0, stream>>>(mat1, mat2, inp, out);
  }
}

// Round 8
// 100.398 us; speedup vs baseline: 1.0904x; 1.0094x over previous
//
#include <hip/hip_runtime.h>

#define MK 4096
#define BK 128

typedef int v4i __attribute__((ext_vector_type(4)));
typedef int v16i __attribute__((ext_vector_type(16)));

#define MFMA32(a, b, c) __builtin_amdgcn_mfma_i32_32x32x32_i8(a, b, c, 0, 0, 0)

#define GLOAD_LDS16(gp, lp) \
  __builtin_amdgcn_global_load_lds((const __attribute__((address_space(1))) void*)(gp), \
                                   (__attribute__((address_space(3))) void*)(lp), 16, 0, 0)

#define SB() __builtin_amdgcn_sched_barrier(0)
#define BARRIER() __builtin_amdgcn_s_barrier()
#define WAIT_VM4() asm volatile("s_waitcnt vmcnt(4)" ::: "memory")
#define WAIT_VM0() asm volatile("s_waitcnt vmcnt(0)" ::: "memory")
#define NOWAIT() ((void)0)

// ------- merged convert: blocks [0,2048) do mat1 int32->int8 (same layout);
//         blocks [2048,6144) do mat2 [K][N] int32 -> [N][K] int8 transpose --
__global__ __launch_bounds__(256) void cvt_kernel(const int* __restrict__ mat1,
                                                  char* __restrict__ A8,
                                                  const int* __restrict__ mat2,
                                                  char* __restrict__ B8T) {
  __shared__ char tile[64][68];
  if (blockIdx.x < 2048) {
    const int n4 = MK * MK / 4;
    int idx = blockIdx.x * 256 + threadIdx.x;
    const int stride = 2048 * 256;
    for (int i = idx; i < n4; i += stride) {
      int4 v = ((const int4*)mat1)[i];
      char4 c;
      c.x = (char)v.x; c.y = (char)v.y; c.z = (char)v.z; c.w = (char)v.w;
      ((char4*)A8)[i] = c;
    }
  } else {
    const int bid = blockIdx.x - 2048;
    const int t = threadIdx.x;
    const int n0 = (bid & 63) * 64, k0 = (bid >> 6) * 64;
#pragma unroll
    for (int r = 0; r < 16; ++r) {
      int k = k0 + r * 4 + (t >> 6);
      int n = n0 + (t & 63);
      tile[t & 63][r * 4 + (t >> 6)] = (char)mat2[(size_t)k * MK + n];
    }
    __syncthreads();
#pragma unroll
    for (int w = 0; w < 4; ++w) {
      int nl = w * 16 + (t >> 4);
      int kl = (t & 15) * 4;
      char4 c = *(const char4*)&tile[nl][kl];
      *(char4*)(B8T + (size_t)(n0 + nl) * MK + k0 + kl) = c;
    }
  }
}

// ---------------- i8 MFMA GEMM, 256x256 tile, 32x32x32 MFMA ----------------
// R13: R11/R8 structure + PARTIAL INTRA-REGION SOFTWARE PIPELINE. R12's skew
// was neutral because it changed WHICH kk waves read post-barrier, not WHEN.
// The remaining main-loop gap (~53us vs ~33us balanced-pipe floor: MFMA 585
// vs LDS-read 578 cyc/phase/CU) is per-wave serialization: reads->wait->
// MFMAs->reads->wait->MFMAs, with both SIMD-mates symmetric, so the MFMA
// pipe drains twice per region. Fix: hoist exactly phase-1's critical-path
// read pair (bg0, ag0 = operands of its first B-major MFMA) to region start;
// phase-1's other 4 reads issue after phase-0's MFMAs with the bg0/ag0 MFMAs
// as cover. Peak live frags 8 v4i (+8 VGPR ~= 244 unified incl. 128 acc) --
// deliberately under the 256-VGPR 2-waves/SIMD cliff; a full 12-read hoist
// (+24) would halve occupancy. R8 FIFO invariants untouched: (a) vmcnt(4)
// waits only on loads >=1 region old; (b) STAGE_A early-region / STAGE_B
// mid-region, write-back spread ~585cyc apart; (c) no wait covers a young
// load. Kept: 4x8 XCD rectangle swizzle (FETCH 106->82MB), merged cvt,
// bf0-first/B-major. Skew dropped (neutral, costs regs).
// LDS half layout (16 KiB): [blk:8][kk:2][r15:16][slot:4][16B],
// slot = (2*khalf + (row>>4)) ^ ((row&15)>>1 & 3)  (R4-verified 0-conflict).
__global__ __launch_bounds__(512, 2) void gemm_i8_kernel(const char* __restrict__ A8,
                                                         const char* __restrict__ B8T,
                                                         const int* __restrict__ inp,
                                                         float* __restrict__ out) {
  extern __shared__ char lds[];
  const int tid = threadIdx.x;
  const int wg = blockIdx.x;
  // XCD-aware 4x8 rectangle swizzle, bijective: xcd = wg&7 owns row-groups
  // [(xcd>>1)*4, +4) x col-groups [(xcd&1)*8, +8).
  const int xcd = wg & 7, loc = wg >> 3;
  const int m0 = (((xcd >> 1) << 2) + (loc >> 3)) << 8;
  const int n0 = (((xcd & 1) << 3) + (loc & 7)) << 8;

  const int lane = tid & 63, wid = tid >> 6;
  const int wr = wid >> 2, wc = wid & 3;
  const int rl = lane & 31;
  const int khalf = lane >> 5;

  // per-lane LDS read base: R2/R4's measured-0-conflict pattern
  const int r15 = lane & 15;
  const int slotr = (lane >> 4) ^ ((r15 >> 1) & 3);
  const char* pAr = lds + wr * 8192 + r15 * 64 + slotr * 16;
  const char* pBr = lds + 65536 + wc * 4096 + r15 * 64 + slotr * 16;

  // staging decode: thread t feeds LDS chunk idx=t (and idx+512 = +4 blks)
  const int sblk = tid >> 7;
  const int skk = (tid >> 6) & 1;
  const int sr15 = (tid >> 2) & 15;
  const int sslot = tid & 3;
  const int sx = sslot ^ ((sr15 >> 1) & 3);
  const int srow = sblk * 32 + (sx & 1) * 16 + sr15;
  const int skb = skk * 32 + (sx >> 1) * 16;
  const char* pA = A8 + (size_t)(m0 + srow) * MK + skb;
  const char* pB = B8T + (size_t)(n0 + srow) * MK + skb;
  char* ldsw = lds + (tid & ~63) * 16;  // wave-uniform dest base (+hw lane*16)

#define STAGE_A_(NB_, H_, TN_) do {                                               \
    const char* s_ = pA + (TN_)*BK + (H_)*64;                                     \
    GLOAD_LDS16(s_,                    ldsw + ((NB_)*32768 + (H_)*16384));        \
    GLOAD_LDS16(s_ + (size_t)128 * MK, ldsw + ((NB_)*32768 + (H_)*16384 + 8192)); \
  } while (0)
#define STAGE_B_(NB_, H_, TN_) do {                                               \
    const char* s_ = pB + (TN_)*BK + (H_)*64;                                     \
    GLOAD_LDS16(s_,                    ldsw + (65536 + (NB_)*32768 + (H_)*16384)); \
    GLOAD_LDS16(s_ + (size_t)128 * MK, ldsw + (65536 + (NB_)*32768 + (H_)*16384 + 8192)); \
  } while (0)

#define AOFF(B_, KK_, MB_) ((B_)*32768 + ((KK_) >> 1) * 16384 + (MB_)*2048 + ((KK_)&1) * 1024)
#define BOFF(B_, KK_, NB_) ((B_)*32768 + ((KK_) >> 1) * 16384 + (NB_)*2048 + ((KK_)&1) * 1024)

// one region = one half-tile (2 kk-steps). Phase-0: 6 reads (bf0-first),
// +2 hoisted phase-1 critical reads (bg0, ag0), STAGE_A, 8 B-major MFMAs.
// Phase-1: remaining 4 reads, STAGE_B, 8 MFMAs. Then the region's ONLY
// sync: SB + vmcnt + barrier + SB. Compiler handles lgkmcnt.
#define REGION(B_, H_, TN_, DOST_, VMW_, DOSYNC_) do {                            \
    bf0 = *(const v4i*)(pBr + BOFF(B_, 2*(H_), 0));                               \
    af0 = *(const v4i*)(pAr + AOFF(B_, 2*(H_), 0));                               \
    af1 = *(const v4i*)(pAr + AOFF(B_, 2*(H_), 1));                               \
    af2 = *(const v4i*)(pAr + AOFF(B_, 2*(H_), 2));                               \
    af3 = *(const v4i*)(pAr + AOFF(B_, 2*(H_), 3));                               \
    bf1 = *(const v4i*)(pBr + BOFF(B_, 2*(H_), 1));                               \
    bg0 = *(const v4i*)(pBr + BOFF(B_, 2*(H_) + 1, 0));                           \
    ag0 = *(const v4i*)(pAr + AOFF(B_, 2*(H_) + 1, 0));                           \
    if (DOST_) STAGE_A_((B_) ^ 1, H_, TN_);                                       \
    __builtin_amdgcn_s_setprio(1);                                                \
    acc[0][0] = MFMA32(af0, bf0, acc[0][0]); acc[1][0] = MFMA32(af1, bf0, acc[1][0]); \
    acc[2][0] = MFMA32(af2, bf0, acc[2][0]); acc[3][0] = MFMA32(af3, bf0, acc[3][0]); \
    acc[0][1] = MFMA32(af0, bf1, acc[0][1]); acc[1][1] = MFMA32(af1, bf1, acc[1][1]); \
    acc[2][1] = MFMA32(af2, bf1, acc[2][1]); acc[3][1] = MFMA32(af3, bf1, acc[3][1]); \
    __builtin_amdgcn_s_setprio(0);                                                \
    ag1 = *(const v4i*)(pAr + AOFF(B_, 2*(H_) + 1, 1));                           \
    ag2 = *(const v4i*)(pAr + AOFF(B_, 2*(H_) + 1, 2));                           \
    ag3 = *(const v4i*)(pAr + AOFF(B_, 2*(H_) + 1, 3));                           \
    bg1 = *(const v4i*)(pBr + BOFF(B_, 2*(H_) + 1, 1));                           \
    if (DOST_) STAGE_B_((B_) ^ 1, H_, TN_);                                       \
    __builtin_amdgcn_s_setprio(1);                                                \
    acc[0][0] = MFMA32(ag0, bg0, acc[0][0]); acc[1][0] = MFMA32(ag1, bg0, acc[1][0]); \
    acc[2][0] = MFMA32(ag2, bg0, acc[2][0]); acc[3][0] = MFMA32(ag3, bg0, acc[3][0]); \
    acc[0][1] = MFMA32(ag0, bg1, acc[0][1]); acc[1][1] = MFMA32(ag1, bg1, acc[1][1]); \
    acc[2][1] = MFMA32(ag2, bg1, acc[2][1]); acc[3][1] = MFMA32(ag3, bg1, acc[3][1]); \
    __builtin_amdgcn_s_setprio(0);                                                \
    if (DOSYNC_) { SB(); VMW_; BARRIER(); SB(); }                                 \
  } while (0)

  v16i acc[4][2];
#pragma unroll
  for (int m = 0; m < 4; ++m)
#pragma unroll
    for (int n = 0; n < 2; ++n)
#pragma unroll
      for (int i = 0; i < 16; ++i) acc[m][n][i] = 0;
  v4i af0, af1, af2, af3, bf0, bf1;
  v4i ag0, ag1, ag2, ag3, bg0, bg1;

  // prologue: stage tile 0 -> buf0 (8 loads), drain h0, sync
  STAGE_A_(0, 0, 0); STAGE_B_(0, 0, 0); STAGE_A_(0, 1, 0); STAGE_B_(0, 1, 0);
  WAIT_VM4(); BARRIER(); SB();

#pragma unroll 1
  for (int it = 0; it < 15; ++it) {
    REGION(0, 0, 2 * it + 1, 1, WAIT_VM4(), 1);
    REGION(0, 1, 2 * it + 1, 1, WAIT_VM4(), 1);
    REGION(1, 0, 2 * it + 2, 1, WAIT_VM4(), 1);
    REGION(1, 1, 2 * it + 2, 1, WAIT_VM4(), 1);
  }
  REGION(0, 0, 31, 1, WAIT_VM4(), 1);
  REGION(0, 1, 31, 1, WAIT_VM4(), 1);
  // tile 31: no staging; region h0 must drain h1's loads before h1 reads
  REGION(1, 0, 0, 0, WAIT_VM0(), 1);
  REGION(1, 1, 0, 0, NOWAIT(), 0);  // last half, no sync needed after

  // epilogue: 32x32 C/D layout col=lane&31, row=(reg&3)+8*(reg>>2)+4*khalf
#pragma unroll
  for (int mb = 0; mb < 4; ++mb) {
#pragma unroll
    for (int nb = 0; nb < 2; ++nb) {
      const int col = n0 + wc * 64 + nb * 32 + rl;
      const int row0 = m0 + wr * 128 + mb * 32 + 4 * khalf;
#pragma unroll
      for (int r = 0; r < 16; ++r) {
        const int row = row0 + (r & 3) + 8 * (r >> 2);
        const size_t idx = (size_t)row * MK + col;
        const int v = acc[mb][nb][r] + __builtin_nontemporal_load(inp + idx);
        __builtin_nontemporal_store((float)v, out + idx);
      }
    }
  }
}

// ---------------- fallback (only if ws too small): naive tiled int32 -------
__global__ void fallback_kernel(const int* __restrict__ mat1, const int* __restrict__ mat2,
                                const int* __restrict__ inp, float* __restrict__ out) {
  __shared__ int As[16][16], Bs[16][17];
  int tx = threadIdx.x, ty = threadIdx.y;
  int row = blockIdx.y * 16 + ty, col = blockIdx.x * 16 + tx;
  int acc = 0;
  for (int kt = 0; kt < MK / 16; ++kt) {
    As[ty][tx] = mat1[(size_t)row * MK + kt * 16 + tx];
    Bs[ty][tx] = mat2[(size_t)(kt * 16 + ty) * MK + col];
    __syncthreads();
#pragma unroll
    for (int k = 0; k < 16; ++k) acc += As[ty][k] * Bs[k][tx];
    __syncthreads();
  }
  size_t idx = (size_t)row * MK + col;
  out[idx] = (float)(acc + inp[idx]);
}

extern "C" void kernel_launch(void* const* d_in, const int* in_sizes, int n_in,
                              void* d_out, int out_size, void* d_ws, size_t ws_size,
                              hipStream_t stream) {
  const int* inp = (const int*)d_in[0];
  const int* mat1 = (const int*)d_in[1];
  const int* mat2 = (const int*)d_in[2];
  float* out = (float*)d_out;

  const size_t need = 2 * (size_t)MK * MK;
  if (ws_size >= need) {
    char* A8 = (char*)d_ws;
    char* B8T = A8 + (size_t)MK * MK;
    cvt_kernel<<<6144, 256, 0, stream>>>(mat1, A8, mat2, B8T);
    (void)hipFuncSetAttribute((const void*)gemm_i8_kernel,
                              hipFuncAttributeMaxDynamicSharedMemorySize, 131072);
    gemm_i8_kernel<<<256, 512, 131072, stream>>>(A8, B8T, inp, out);
  } else {
    dim3 blk(16, 16), grd(MK / 16, MK / 16);
    fallback_kernel<<<grd, blk, 0, stream>>>(mat1, mat2, inp, out);
  }
}